// Round 5
// baseline (2240.749 us; speedup 1.0000x reference)
//
#include <hip/hip_runtime.h>
#include <hip/hip_fp16.h>

#define D 128
#define N_ITER 20
#define HBITS 15                  // 32768 nodes per range
#define HWORDS (1 << (HBITS - 1)) // 16384 packed uint16-pair words = 64 KB LDS

// ---------------- mask dtype detection (sampled prefix is sufficient) ----------------
__global__ void k_detect(const unsigned char* __restrict__ m, int nbytes, int* flag) {
    __shared__ int s;
    if (threadIdx.x == 0) s = 0;
    __syncthreads();
    int c = 0;
    for (int i = threadIdx.x; i < nbytes; i += 256)
        if ((i & 3) && m[i]) c++;
    atomicAdd(&s, c);
    __syncthreads();
    if (threadIdx.x == 0) *flag = (s > 0) ? 1 : 0;
}

__global__ void k_mask(const void* __restrict__ mraw, const int* __restrict__ flag,
                       unsigned char* __restrict__ m8, int* __restrict__ nm, int n) {
    int i = blockIdx.x * 256 + threadIdx.x;
    if (i >= n) return;
    unsigned char v;
    if (*flag) {
        v = ((const unsigned char*)mraw)[i] != 0;
    } else {
        v = ((const int*)mraw)[i] != 0;
    }
    m8[i] = v;
    nm[i] = v ? 0 : 1;
}

// ---------------- histogram: range-partitioned, LDS-privatized, packed u16 ----------
__global__ __launch_bounds__(256) void k_hist(const int* __restrict__ keys, int E,
                                              int Bp, int per,
                                              unsigned int* __restrict__ sc) {
    __shared__ unsigned int h[HWORDS];
    int r = blockIdx.x / Bp;
    int b = blockIdx.x - r * Bp;
    for (int i = threadIdx.x; i < HWORDS; i += 256) h[i] = 0;
    __syncthreads();
    int lo = r << HBITS;
    int beg = b * per;
    int end = min(beg + per, E);
    int e = beg + (threadIdx.x << 2);
    for (; e + 3 < end; e += 1024) {
        int4 k4 = *(const int4*)(keys + e);
        int k;
        k = k4.x - lo; if ((unsigned)k < (unsigned)(1 << HBITS)) atomicAdd(&h[k >> 1], 1u << ((k & 1) << 4));
        k = k4.y - lo; if ((unsigned)k < (unsigned)(1 << HBITS)) atomicAdd(&h[k >> 1], 1u << ((k & 1) << 4));
        k = k4.z - lo; if ((unsigned)k < (unsigned)(1 << HBITS)) atomicAdd(&h[k >> 1], 1u << ((k & 1) << 4));
        k = k4.w - lo; if ((unsigned)k < (unsigned)(1 << HBITS)) atomicAdd(&h[k >> 1], 1u << ((k & 1) << 4));
    }
    for (int ee = e; ee < end && ee < e + 4; ee++) {
        int k = keys[ee] - lo;
        if ((unsigned)k < (unsigned)(1 << HBITS)) atomicAdd(&h[k >> 1], 1u << ((k & 1) << 4));
    }
    __syncthreads();
    unsigned int* out = sc + ((size_t)blockIdx.x << (HBITS - 1));
    for (int i = threadIdx.x; i < HWORDS; i += 256) out[i] = h[i];
}

// ---------------- reduce per-block histograms -> dis (MODE 0) or rdeg (MODE 1) ------
template <int MODE>
__global__ void k_red(const unsigned int* __restrict__ sc, int Bp,
                      const unsigned char* __restrict__ m8,
                      float* __restrict__ dis, int* __restrict__ rdeg, int N, int R) {
    int w = blockIdx.x * 256 + threadIdx.x;
    if (w >= (R << (HBITS - 1))) return;
    int r = w >> (HBITS - 1);
    int word = w & (HWORDS - 1);
    int n0 = (r << HBITS) + (word << 1);
    if (n0 >= N) return;
    const unsigned int* p = sc + (((size_t)r * Bp) << (HBITS - 1)) + word;
    unsigned int slo = 0, shi = 0;
    for (int b = 0; b < Bp; b++) {
        unsigned int v = p[(size_t)b << (HBITS - 1)];
        slo += v & 0xffffu;
        shi += v >> 16;
    }
    if (MODE == 0) {
        dis[n0] = slo ? rsqrtf((float)slo) : 0.f;
        if (n0 + 1 < N) dis[n0 + 1] = shi ? rsqrtf((float)shi) : 0.f;
    } else {
        rdeg[n0] = m8[n0] ? 0 : (int)slo;
        if (n0 + 1 < N) rdeg[n0 + 1] = m8[n0 + 1] ? 0 : (int)shi;
    }
}

// ---------------- exclusive scan (generic over input array) ----------------
__global__ void k_scan1(const int* __restrict__ a, int* __restrict__ csum, int n) {
    __shared__ int sh[256];
    int base = blockIdx.x * 2048;
    int t = threadIdx.x;
    int s = 0;
    for (int j = 0; j < 8; j++) {
        int i = base + t * 8 + j;
        if (i < n) s += a[i];
    }
    sh[t] = s;
    __syncthreads();
    for (int o = 128; o > 0; o >>= 1) {
        if (t < o) sh[t] += sh[t + o];
        __syncthreads();
    }
    if (t == 0) csum[blockIdx.x] = sh[0];
}

__global__ void k_scan2(int* __restrict__ csum, int nch, int* __restrict__ out_off, int n) {
    if (threadIdx.x == 0) {
        int acc = 0;
        for (int i = 0; i < nch; i++) { int v = csum[i]; csum[i] = acc; acc += v; }
        out_off[n] = acc;
    }
}

__global__ void k_scan3(const int* __restrict__ a, const int* __restrict__ csum,
                        int* __restrict__ out_off, int n) {
    __shared__ int sh[256];
    int base = blockIdx.x * 2048;
    int t = threadIdx.x;
    int loc[8];
    int s = 0;
    for (int j = 0; j < 8; j++) {
        int i = base + t * 8 + j;
        int v = (i < n) ? a[i] : 0;
        loc[j] = s;
        s += v;
    }
    sh[t] = s;
    __syncthreads();
    for (int o = 1; o < 256; o <<= 1) {
        int v = (t >= o) ? sh[t - o] : 0;
        __syncthreads();
        sh[t] += v;
        __syncthreads();
    }
    int toff = csum[blockIdx.x] + ((t > 0) ? sh[t - 1] : 0);
    for (int j = 0; j < 8; j++) {
        int i = base + t * 8 + j;
        if (i < n) out_off[i] = toff + loc[j];
    }
}

// ---------------- ordered compact: rows_c[cpos[i]] = i for unmasked i ----------------
__global__ void k_fill(const unsigned char* __restrict__ m8, const int* __restrict__ cpos,
                       int* __restrict__ rows_c, int n) {
    int i = blockIdx.x * 256 + threadIdx.x;
    if (i >= n) return;
    if (!m8[i]) rows_c[cpos[i]] = i;
}

// ---------------- scatter: masked cols (orig id) front / unmasked cols (compact) back
__global__ void k_scatter(const int* __restrict__ row, const int* __restrict__ col, int E,
                          const unsigned char* __restrict__ m8,
                          const int* __restrict__ row_off,
                          const int* __restrict__ cpos,
                          int* __restrict__ cur_m, int* __restrict__ cur_u,
                          int* __restrict__ col_s) {
    int e = blockIdx.x * 256 + threadIdx.x;
    if (e >= E) return;
    int r = row[e];
    if (m8[r]) return;
    int c = col[e];
    int p;
    if (m8[c]) {
        p = row_off[r] + atomicAdd(&cur_m[r], 1);
        col_s[p] = c;                 // original id: k_sfix gathers x[c]
    } else {
        p = row_off[r + 1] - 1 - atomicAdd(&cur_u[r], 1);
        col_s[p] = cpos[c];           // compact id: k_iter gathers dense u
    }
}

// ---------------- per-row descriptors: one 16B load replaces a dependent chain -------
__global__ void k_desc(const int* __restrict__ rows_c, const int* __restrict__ cnt_p,
                       const int* __restrict__ row_off, const int* __restrict__ cur_m,
                       int4* __restrict__ di, int4* __restrict__ dsx) {
    int i = blockIdx.x * 256 + threadIdx.x;
    if (i >= *cnt_p) return;
    int r = rows_c[i];
    int ro = row_off[r];
    int cm = cur_m[r];
    int ro1 = row_off[r + 1];
    di[i]  = make_int4(r, ro + cm, ro1, 0);   // unmasked-col edge range (per-iteration gather)
    dsx[i] = make_int4(r, ro, ro + cm, 0);    // masked-col edge range (S_fix)
}

// ---------------- init: masked rows of d_out = x ----------------
__global__ void k_init(const float* __restrict__ x, const unsigned char* __restrict__ m8,
                       float* __restrict__ out, int nvec) {
    int i = blockIdx.x * 256 + threadIdx.x;  // float4 index, 32 per node
    if (i >= nvec) return;
    int node = i >> 5;
    if (m8[node]) ((float4*)out)[i] = ((const float4*)x)[i];
}

// ---------------- S_fix[i] = sum over masked cols of dis[c]*x[c]  -------------------
// Stores S and u1 = dis^2*S in CHUNKED compact fp16 layout:
//   chunk j (32 feats, 64B) of compact row i lives at uint2 index (j*cn + i)*8 + 0..7
__global__ __launch_bounds__(256) void k_sfix(const float* __restrict__ x,
                                              const float* __restrict__ dis,
                                              const int4* __restrict__ desc,
                                              const int* __restrict__ cnt_p,
                                              const int* __restrict__ col_s,
                                              uint2* __restrict__ S,
                                              uint2* __restrict__ u1) {
    int wgid = (blockIdx.x * 256 + threadIdx.x) >> 6;
    int lane = threadIdx.x & 63;
    int nw = gridDim.x << 2;
    int cn = *cnt_p;

    int s = lane >> 5;     // edge slot 0..1
    int f = lane & 31;     // float4 slot within 512B row
    const float4* xb = (const float4*)x + f;
    int jch = f >> 3;      // output chunk
    int fq = f & 7;        // uint2 slot within 64B chunk row

    for (int wid = wgid; wid < cn; wid += nw) {
        int4 dsc = desc[wid];
        int r   = __builtin_amdgcn_readfirstlane(dsc.x);
        int beg = __builtin_amdgcn_readfirstlane(dsc.y);
        int end = __builtin_amdgcn_readfirstlane(dsc.z);

        float a0 = 0, a1 = 0, a2 = 0, a3 = 0;
        float b0 = 0, b1 = 0, b2 = 0, b3 = 0;
        int e = beg;
        for (; e + 8 <= end; e += 8) {
            int c0 = col_s[e + s],     c1 = col_s[e + 2 + s];
            int c2 = col_s[e + 4 + s], c3 = col_s[e + 6 + s];
            float w0 = dis[c0], w1 = dis[c1], w2 = dis[c2], w3 = dis[c3];
            float4 v0 = xb[(size_t)c0 * 32];
            float4 v1 = xb[(size_t)c1 * 32];
            float4 v2 = xb[(size_t)c2 * 32];
            float4 v3 = xb[(size_t)c3 * 32];
            a0 += w0 * v0.x; a1 += w0 * v0.y; a2 += w0 * v0.z; a3 += w0 * v0.w;
            b0 += w1 * v1.x; b1 += w1 * v1.y; b2 += w1 * v1.z; b3 += w1 * v1.w;
            a0 += w2 * v2.x; a1 += w2 * v2.y; a2 += w2 * v2.z; a3 += w2 * v2.w;
            b0 += w3 * v3.x; b1 += w3 * v3.y; b2 += w3 * v3.z; b3 += w3 * v3.w;
        }
        for (; e + 2 <= end; e += 2) {
            int c = col_s[e + s];
            float w = dis[c];
            float4 v = xb[(size_t)c * 32];
            a0 += w * v.x; a1 += w * v.y; a2 += w * v.z; a3 += w * v.w;
        }
        if (e < end && s == 0) {
            int c = col_s[e];
            float w = dis[c];
            float4 v = xb[(size_t)c * 32];
            a0 += w * v.x; a1 += w * v.y; a2 += w * v.z; a3 += w * v.w;
        }
        a0 += b0; a1 += b1; a2 += b2; a3 += b3;
        a0 += __shfl_xor(a0, 32, 64);
        a1 += __shfl_xor(a1, 32, 64);
        a2 += __shfl_xor(a2, 32, 64);
        a3 += __shfl_xor(a3, 32, 64);
        if (lane < 32) {
            size_t so = ((size_t)jch * cn + wid) * 8 + fq;
            __half2 h0 = __floats2half2_rn(a0, a1);
            __half2 h1 = __floats2half2_rn(a2, a3);
            uint2 o;
            __builtin_memcpy(&o.x, &h0, 4);
            __builtin_memcpy(&o.y, &h1, 4);
            S[so] = o;
            float dd = dis[r];
            float ss = dd * dd;
            __half2 g0 = __floats2half2_rn(ss * a0, ss * a1);
            __half2 g1 = __floats2half2_rn(ss * a2, ss * a3);
            uint2 o2;
            __builtin_memcpy(&o2.x, &g0, 4);
            __builtin_memcpy(&o2.y, &g1, 4);
            u1[so] = o2;
        }
    }
}

// ---------------- iteration: chunk-phased, L2-resident dense gather ------------------
// u layout (fp16): dword index (j*cn + i)*16 + q, q=0..15 (chunk j = feats 32j..32j+31).
// Phase j processed by ALL waves before j+1 (j-outer, grid-stride-i-inner, persistent
// grid co-resident) -> per-XCD L2 holds the 3.2MB chunk image; gathers become L2 hits.
template <bool FINAL>
__global__ __launch_bounds__(256) void k_iter(const unsigned int* __restrict__ src,
                                              void* __restrict__ dst,
                                              const unsigned int* __restrict__ S,
                                              const int4* __restrict__ desc,
                                              const int* __restrict__ cnt_p,
                                              const int* __restrict__ col_s,
                                              const float* __restrict__ dis) {
    int wgid = (blockIdx.x * 256 + threadIdx.x) >> 6;
    int lane = threadIdx.x & 63;
    int nw = gridDim.x << 2;
    int cn = *cnt_p;

    int s = lane >> 4;     // edge slot 0..3
    int q = lane & 15;     // dword slot within 64B chunk row

    for (int j = 0; j < 4; j++) {
        const unsigned int* sj = src + ((size_t)j * cn) * 16 + q;
        const unsigned int* Sj = S + ((size_t)j * cn) * 16 + q;
        unsigned int* dj = (unsigned int*)dst + ((size_t)j * cn) * 16 + q;
        for (int i = wgid; i < cn; i += nw) {
            int4 dsc = desc[i];
            int r   = __builtin_amdgcn_readfirstlane(dsc.x);
            int beg = __builtin_amdgcn_readfirstlane(dsc.y);
            int end = __builtin_amdgcn_readfirstlane(dsc.z);

            float a0 = 0.f, a1 = 0.f, b0 = 0.f, b1 = 0.f;
            if (s == 0) {
                unsigned int sv = __builtin_nontemporal_load(Sj + (size_t)i * 16);
                __half2 h; __builtin_memcpy(&h, &sv, 4);
                float2 v = __half22float2(h);
                a0 = v.x; a1 = v.y;
            }
            int e = beg;
            for (; e + 8 <= end; e += 8) {
                int c0 = __builtin_nontemporal_load(col_s + e + s);
                int c1 = __builtin_nontemporal_load(col_s + e + 4 + s);
                unsigned int g0 = sj[(size_t)c0 * 16];
                unsigned int g1 = sj[(size_t)c1 * 16];
                __half2 h; float2 v;
                __builtin_memcpy(&h, &g0, 4); v = __half22float2(h); a0 += v.x; a1 += v.y;
                __builtin_memcpy(&h, &g1, 4); v = __half22float2(h); b0 += v.x; b1 += v.y;
            }
            for (; e + 4 <= end; e += 4) {
                int c = __builtin_nontemporal_load(col_s + e + s);
                unsigned int g = sj[(size_t)c * 16];
                __half2 h; __builtin_memcpy(&h, &g, 4);
                float2 v = __half22float2(h);
                a0 += v.x; a1 += v.y;
            }
            int rem = end - e;
            if (s < rem) {
                int c = __builtin_nontemporal_load(col_s + e + s);
                unsigned int g = sj[(size_t)c * 16];
                __half2 h; __builtin_memcpy(&h, &g, 4);
                float2 v = __half22float2(h);
                a0 += v.x; a1 += v.y;
            }
            a0 += b0; a1 += b1;
            a0 += __shfl_xor(a0, 16, 64); a0 += __shfl_xor(a0, 32, 64);
            a1 += __shfl_xor(a1, 16, 64); a1 += __shfl_xor(a1, 32, 64);

            if (s == 0) {
                float d = dis[r];
                if (FINAL) {
                    float2* o = (float2*)dst + (size_t)r * 64 + j * 16 + q;
                    *o = make_float2(d * a0, d * a1);
                } else {
                    float ss = d * d;
                    __half2 h = __floats2half2_rn(ss * a0, ss * a1);
                    unsigned int o; __builtin_memcpy(&o, &h, 4);
                    __builtin_nontemporal_store(o, dj + (size_t)i * 16);
                }
            }
        }
    }
}

extern "C" void kernel_launch(void* const* d_in, const int* in_sizes, int n_in,
                              void* d_out, int out_size, void* d_ws, size_t ws_size,
                              hipStream_t stream) {
    const float* x = (const float*)d_in[0];
    const int* ei = (const int*)d_in[1];
    const void* mraw = d_in[2];

    const int N = in_sizes[0] / D;     // 100000
    const int E = in_sizes[1] / 2;     // 3200000
    const int* row = ei;
    const int* col = ei + E;

    char* ws = (char*)d_ws;
    size_t off = 0;
    uint2* uA = (uint2*)(ws + off);         off += (size_t)N * D * 2;   // fp16 u buffers (chunked)
    uint2* uB = (uint2*)(ws + off);         off += (size_t)N * D * 2;
    uint2* S  = (uint2*)(ws + off);         off += (size_t)N * D * 2;   // fp16 S_fix (chunked)
    int* col_s = (int*)(ws + off);          off += (size_t)E * 4;       // CSR cols (filtered, split)
    int* row_off = (int*)(ws + off);        off += (size_t)(N + 1) * 4;
    int* zblock = (int*)(ws + off);         off += (size_t)(2 * N) * 4; // cur_m|cur_u (memset)
    int* cur_m = zblock;
    int* cur_u = zblock + N;
    int* rdeg = (int*)(ws + off);           off += (size_t)N * 4;
    float* dis = (float*)(ws + off);        off += (size_t)N * 4;
    int* rows_c = (int*)(ws + off);         off += (size_t)N * 4;
    int* nm = (int*)(ws + off);             off += (size_t)N * 4;
    int* cpos = (int*)(ws + off);           off += (size_t)(N + 1) * 4;
    unsigned char* m8 = (unsigned char*)(ws + off); off += (size_t)N;
    off = (off + 255) & ~(size_t)255;
    int* csum = (int*)(ws + off);           off += 256 * 4;
    int* csum2 = (int*)(ws + off);          off += 256 * 4;
    int* flag = (int*)(ws + off);           off += 4;
    off = (off + 255) & ~(size_t)255;
    int4* desc_i = (int4*)(ws + off);       off += (size_t)N * 16;
    int4* desc_s = (int4*)(ws + off);       off += (size_t)N * 16;

    const int* cnt_p = cpos + N;   // total unmasked count, written by scan

    // histogram scratch: aliases uA+uB (written only later by k_sfix / k_iter)
    unsigned int* sc = (unsigned int*)ws;

    (void)hipMemsetAsync(zblock, 0, (size_t)(2 * N) * 4, stream);

    int nb = N < 16384 ? N : 16384;
    k_detect<<<1, 256, 0, stream>>>((const unsigned char*)mraw, nb, flag);
    k_mask<<<(N + 255) / 256, 256, 0, stream>>>(mraw, flag, m8, nm, N);

    // degree histograms: col -> dis, row -> rdeg (mask applied at reduce)
    const int R = (N + (1 << HBITS) - 1) >> HBITS;   // 4 ranges of 32768
    const int Bp = 128;                              // slice <= 25008 < 65536
    int per = ((E + Bp - 1) / Bp + 15) & ~15;
    int rwords = (R << (HBITS - 1));
    k_hist<<<R * Bp, 256, 0, stream>>>(col, E, Bp, per, sc);
    k_red<0><<<(rwords + 255) / 256, 256, 0, stream>>>(sc, Bp, m8, dis, rdeg, N, R);
    k_hist<<<R * Bp, 256, 0, stream>>>(row, E, Bp, per, sc);
    k_red<1><<<(rwords + 255) / 256, 256, 0, stream>>>(sc, Bp, m8, dis, rdeg, N, R);

    int nch = (N + 2047) / 2048;
    // scan rdeg -> row_off
    k_scan1<<<nch, 256, 0, stream>>>(rdeg, csum, N);
    k_scan2<<<1, 64, 0, stream>>>(csum, nch, row_off, N);
    k_scan3<<<nch, 256, 0, stream>>>(rdeg, csum, row_off, N);
    // scan !mask -> cpos (ordered compaction positions), cpos[N] = cnt
    k_scan1<<<nch, 256, 0, stream>>>(nm, csum2, N);
    k_scan2<<<1, 64, 0, stream>>>(csum2, nch, cpos, N);
    k_scan3<<<nch, 256, 0, stream>>>(nm, csum2, cpos, N);
    k_fill<<<(N + 255) / 256, 256, 0, stream>>>(m8, cpos, rows_c, N);

    k_scatter<<<(E + 255) / 256, 256, 0, stream>>>(row, col, E, m8, row_off, cpos,
                                                   cur_m, cur_u, col_s);
    k_desc<<<(N + 255) / 256, 256, 0, stream>>>(rows_c, cnt_p, row_off, cur_m, desc_i, desc_s);

    int nvec = N * (D / 4);
    k_init<<<(nvec + 255) / 256, 256, 0, stream>>>(x, m8, (float*)d_out, nvec);

    const int PBLK = 2048;   // persistent grid: 8192 waves, all co-resident (8 blk/CU)
    k_sfix<<<PBLK, 256, 0, stream>>>(x, dis, desc_s, cnt_p, col_s, S, uA);

    // u1 in uA; 18 fp16 chunk-phased iterations, then final fp32 iteration -> d_out
    unsigned int* src = (unsigned int*)uA;
    unsigned int* dst = (unsigned int*)uB;
    const unsigned int* Sd = (const unsigned int*)S;
    for (int it = 0; it < N_ITER - 2; it++) {
        k_iter<false><<<PBLK, 256, 0, stream>>>(src, dst, Sd, desc_i, cnt_p, col_s, dis);
        unsigned int* t = src; src = dst; dst = t;
    }
    k_iter<true><<<PBLK, 256, 0, stream>>>(src, d_out, Sd, desc_i, cnt_p, col_s, dis);
}

// Round 7
// 1548.181 us; speedup vs baseline: 1.4473x; 1.4473x over previous
//
#include <hip/hip_runtime.h>
#include <hip/hip_fp16.h>

// Round 6 retry: previous submission failed in the broker (container failed twice,
// no kernel verdict). Source is functionally identical to the Round-6 kernel.

#define D 128
#define N_ITER 20
#define HBITS 15                  // 32768 nodes per range
#define HWORDS (1 << (HBITS - 1)) // 16384 packed uint16-pair words = 64 KB LDS

// ---------------- mask dtype detection (sampled prefix is sufficient) ----------------
__global__ void k_detect(const unsigned char* __restrict__ m, int nbytes, int* flag) {
    __shared__ int s;
    if (threadIdx.x == 0) s = 0;
    __syncthreads();
    int c = 0;
    for (int i = threadIdx.x; i < nbytes; i += 256)
        if ((i & 3) && m[i]) c++;
    atomicAdd(&s, c);
    __syncthreads();
    if (threadIdx.x == 0) *flag = (s > 0) ? 1 : 0;
}

__global__ void k_mask(const void* __restrict__ mraw, const int* __restrict__ flag,
                       unsigned char* __restrict__ m8, int* __restrict__ nm, int n) {
    int i = blockIdx.x * 256 + threadIdx.x;
    if (i >= n) return;
    unsigned char v;
    if (*flag) {
        v = ((const unsigned char*)mraw)[i] != 0;
    } else {
        v = ((const int*)mraw)[i] != 0;
    }
    m8[i] = v;
    nm[i] = v ? 0 : 1;
}

// ---------------- histogram: range-partitioned, LDS-privatized, packed u16 ----------
__global__ __launch_bounds__(256) void k_hist(const int* __restrict__ keys, int E,
                                              int Bp, int per,
                                              unsigned int* __restrict__ sc) {
    __shared__ unsigned int h[HWORDS];
    int r = blockIdx.x / Bp;
    int b = blockIdx.x - r * Bp;
    for (int i = threadIdx.x; i < HWORDS; i += 256) h[i] = 0;
    __syncthreads();
    int lo = r << HBITS;
    int beg = b * per;
    int end = min(beg + per, E);
    int e = beg + (threadIdx.x << 2);
    for (; e + 3 < end; e += 1024) {
        int4 k4 = *(const int4*)(keys + e);
        int k;
        k = k4.x - lo; if ((unsigned)k < (unsigned)(1 << HBITS)) atomicAdd(&h[k >> 1], 1u << ((k & 1) << 4));
        k = k4.y - lo; if ((unsigned)k < (unsigned)(1 << HBITS)) atomicAdd(&h[k >> 1], 1u << ((k & 1) << 4));
        k = k4.z - lo; if ((unsigned)k < (unsigned)(1 << HBITS)) atomicAdd(&h[k >> 1], 1u << ((k & 1) << 4));
        k = k4.w - lo; if ((unsigned)k < (unsigned)(1 << HBITS)) atomicAdd(&h[k >> 1], 1u << ((k & 1) << 4));
    }
    for (int ee = e; ee < end && ee < e + 4; ee++) {
        int k = keys[ee] - lo;
        if ((unsigned)k < (unsigned)(1 << HBITS)) atomicAdd(&h[k >> 1], 1u << ((k & 1) << 4));
    }
    __syncthreads();
    unsigned int* out = sc + ((size_t)blockIdx.x << (HBITS - 1));
    for (int i = threadIdx.x; i < HWORDS; i += 256) out[i] = h[i];
}

// ---------------- reduce per-block histograms -> dis (MODE 0) or rdeg (MODE 1) ------
template <int MODE>
__global__ void k_red(const unsigned int* __restrict__ sc, int Bp,
                      const unsigned char* __restrict__ m8,
                      float* __restrict__ dis, int* __restrict__ rdeg, int N, int R) {
    int w = blockIdx.x * 256 + threadIdx.x;
    if (w >= (R << (HBITS - 1))) return;
    int r = w >> (HBITS - 1);
    int word = w & (HWORDS - 1);
    int n0 = (r << HBITS) + (word << 1);
    if (n0 >= N) return;
    const unsigned int* p = sc + (((size_t)r * Bp) << (HBITS - 1)) + word;
    unsigned int slo = 0, shi = 0;
    for (int b = 0; b < Bp; b++) {
        unsigned int v = p[(size_t)b << (HBITS - 1)];
        slo += v & 0xffffu;
        shi += v >> 16;
    }
    if (MODE == 0) {
        dis[n0] = slo ? rsqrtf((float)slo) : 0.f;
        if (n0 + 1 < N) dis[n0 + 1] = shi ? rsqrtf((float)shi) : 0.f;
    } else {
        rdeg[n0] = m8[n0] ? 0 : (int)slo;
        if (n0 + 1 < N) rdeg[n0 + 1] = m8[n0 + 1] ? 0 : (int)shi;
    }
}

// ---------------- exclusive scan (generic over input array) ----------------
__global__ void k_scan1(const int* __restrict__ a, int* __restrict__ csum, int n) {
    __shared__ int sh[256];
    int base = blockIdx.x * 2048;
    int t = threadIdx.x;
    int s = 0;
    for (int j = 0; j < 8; j++) {
        int i = base + t * 8 + j;
        if (i < n) s += a[i];
    }
    sh[t] = s;
    __syncthreads();
    for (int o = 128; o > 0; o >>= 1) {
        if (t < o) sh[t] += sh[t + o];
        __syncthreads();
    }
    if (t == 0) csum[blockIdx.x] = sh[0];
}

__global__ void k_scan2(int* __restrict__ csum, int nch, int* __restrict__ out_off, int n) {
    if (threadIdx.x == 0) {
        int acc = 0;
        for (int i = 0; i < nch; i++) { int v = csum[i]; csum[i] = acc; acc += v; }
        out_off[n] = acc;
    }
}

__global__ void k_scan3(const int* __restrict__ a, const int* __restrict__ csum,
                        int* __restrict__ out_off, int n) {
    __shared__ int sh[256];
    int base = blockIdx.x * 2048;
    int t = threadIdx.x;
    int loc[8];
    int s = 0;
    for (int j = 0; j < 8; j++) {
        int i = base + t * 8 + j;
        int v = (i < n) ? a[i] : 0;
        loc[j] = s;
        s += v;
    }
    sh[t] = s;
    __syncthreads();
    for (int o = 1; o < 256; o <<= 1) {
        int v = (t >= o) ? sh[t - o] : 0;
        __syncthreads();
        sh[t] += v;
        __syncthreads();
    }
    int toff = csum[blockIdx.x] + ((t > 0) ? sh[t - 1] : 0);
    for (int j = 0; j < 8; j++) {
        int i = base + t * 8 + j;
        if (i < n) out_off[i] = toff + loc[j];
    }
}

// ---------------- ordered compact: rows_c[cpos[i]] = i for unmasked i ----------------
__global__ void k_fill(const unsigned char* __restrict__ m8, const int* __restrict__ cpos,
                       int* __restrict__ rows_c, int n) {
    int i = blockIdx.x * 256 + threadIdx.x;
    if (i >= n) return;
    if (!m8[i]) rows_c[cpos[i]] = i;
}

// ---------------- scatter: masked cols (orig id) front / unmasked cols (compact) back
__global__ void k_scatter(const int* __restrict__ row, const int* __restrict__ col, int E,
                          const unsigned char* __restrict__ m8,
                          const int* __restrict__ row_off,
                          const int* __restrict__ cpos,
                          int* __restrict__ cur_m, int* __restrict__ cur_u,
                          int* __restrict__ col_s) {
    int e = blockIdx.x * 256 + threadIdx.x;
    if (e >= E) return;
    int r = row[e];
    if (m8[r]) return;
    int c = col[e];
    int p;
    if (m8[c]) {
        p = row_off[r] + atomicAdd(&cur_m[r], 1);
        col_s[p] = c;                 // original id: k_sfix gathers x[c]
    } else {
        p = row_off[r + 1] - 1 - atomicAdd(&cur_u[r], 1);
        col_s[p] = cpos[c];           // compact id: k_iter gathers dense u
    }
}

// ---------------- per-row descriptors; .w carries dis[r] bits ----------------
__global__ void k_desc(const int* __restrict__ rows_c, const int* __restrict__ cnt_p,
                       const int* __restrict__ row_off, const int* __restrict__ cur_m,
                       const float* __restrict__ dis,
                       int4* __restrict__ di, int4* __restrict__ dsx) {
    int i = blockIdx.x * 256 + threadIdx.x;
    if (i >= *cnt_p) return;
    int r = rows_c[i];
    int ro = row_off[r];
    int cm = cur_m[r];
    int ro1 = row_off[r + 1];
    int db = __float_as_int(dis[r]);
    di[i]  = make_int4(r, ro + cm, ro1, db);  // unmasked-col edge range (per-iteration gather)
    dsx[i] = make_int4(r, ro, ro + cm, db);   // masked-col edge range (S_fix)
}

// ---------------- init: masked rows of d_out = x ----------------
__global__ void k_init(const float* __restrict__ x, const unsigned char* __restrict__ m8,
                       float* __restrict__ out, int nvec) {
    int i = blockIdx.x * 256 + threadIdx.x;  // float4 index, 32 per node
    if (i >= nvec) return;
    int node = i >> 5;
    if (m8[node]) ((float4*)out)[i] = ((const float4*)x)[i];
}

// ---------------- S_fix[i] = sum over masked cols of dis[c]*x[c]  -------------------
// Stores S and u1 = dis^2*S in CHUNKED compact fp16 layout:
//   chunk j (32 feats, 64B) of compact row i lives at uint2 index (j*cn + i)*8 + 0..7
__global__ __launch_bounds__(256) void k_sfix(const float* __restrict__ x,
                                              const float* __restrict__ dis,
                                              const int4* __restrict__ desc,
                                              const int* __restrict__ cnt_p,
                                              const int* __restrict__ col_s,
                                              uint2* __restrict__ S,
                                              uint2* __restrict__ u1) {
    int wgid = (blockIdx.x * 256 + threadIdx.x) >> 6;
    int lane = threadIdx.x & 63;
    int nw = gridDim.x << 2;
    int cn = *cnt_p;

    int s = lane >> 5;     // edge slot 0..1
    int f = lane & 31;     // float4 slot within 512B row
    const float4* xb = (const float4*)x + f;
    int jch = f >> 3;      // output chunk
    int fq = f & 7;        // uint2 slot within 64B chunk row

    for (int wid = wgid; wid < cn; wid += nw) {
        int4 dsc = desc[wid];
        int beg = __builtin_amdgcn_readfirstlane(dsc.y);
        int end = __builtin_amdgcn_readfirstlane(dsc.z);

        float a0 = 0, a1 = 0, a2 = 0, a3 = 0;
        float b0 = 0, b1 = 0, b2 = 0, b3 = 0;
        int e = beg;
        for (; e + 8 <= end; e += 8) {
            int c0 = col_s[e + s],     c1 = col_s[e + 2 + s];
            int c2 = col_s[e + 4 + s], c3 = col_s[e + 6 + s];
            float w0 = dis[c0], w1 = dis[c1], w2 = dis[c2], w3 = dis[c3];
            float4 v0 = xb[(size_t)c0 * 32];
            float4 v1 = xb[(size_t)c1 * 32];
            float4 v2 = xb[(size_t)c2 * 32];
            float4 v3 = xb[(size_t)c3 * 32];
            a0 += w0 * v0.x; a1 += w0 * v0.y; a2 += w0 * v0.z; a3 += w0 * v0.w;
            b0 += w1 * v1.x; b1 += w1 * v1.y; b2 += w1 * v1.z; b3 += w1 * v1.w;
            a0 += w2 * v2.x; a1 += w2 * v2.y; a2 += w2 * v2.z; a3 += w2 * v2.w;
            b0 += w3 * v3.x; b1 += w3 * v3.y; b2 += w3 * v3.z; b3 += w3 * v3.w;
        }
        for (; e + 2 <= end; e += 2) {
            int c = col_s[e + s];
            float w = dis[c];
            float4 v = xb[(size_t)c * 32];
            a0 += w * v.x; a1 += w * v.y; a2 += w * v.z; a3 += w * v.w;
        }
        if (e < end && s == 0) {
            int c = col_s[e];
            float w = dis[c];
            float4 v = xb[(size_t)c * 32];
            a0 += w * v.x; a1 += w * v.y; a2 += w * v.z; a3 += w * v.w;
        }
        a0 += b0; a1 += b1; a2 += b2; a3 += b3;
        a0 += __shfl_xor(a0, 32, 64);
        a1 += __shfl_xor(a1, 32, 64);
        a2 += __shfl_xor(a2, 32, 64);
        a3 += __shfl_xor(a3, 32, 64);
        if (lane < 32) {
            size_t so = ((size_t)jch * cn + wid) * 8 + fq;
            __half2 h0 = __floats2half2_rn(a0, a1);
            __half2 h1 = __floats2half2_rn(a2, a3);
            uint2 o;
            __builtin_memcpy(&o.x, &h0, 4);
            __builtin_memcpy(&o.y, &h1, 4);
            S[so] = o;
            float dd = __int_as_float(dsc.w);
            float ss = dd * dd;
            __half2 g0 = __floats2half2_rn(ss * a0, ss * a1);
            __half2 g1 = __floats2half2_rn(ss * a2, ss * a3);
            uint2 o2;
            __builtin_memcpy(&o2.x, &g0, 4);
            __builtin_memcpy(&o2.y, &g1, 4);
            u1[so] = o2;
        }
    }
}

// ---------------- iteration: chunk-phased, XCD-staggered, L2-resident dense gather ---
// u layout (fp16): uint2 index (j*cn + i)*8 + q, q=0..7 (chunk j = feats 32j..32j+31).
// Chunks are feature-separable, so any processing order is valid; each XCD starts at
// its own chunk (blockIdx&3 under round-robin block->XCD dispatch) so its private L2
// holds one 3.2MB chunk image regardless of cross-XCD drift. No nontemporal hints:
// the u buffers MUST cache (NT stores caused 90MB/dispatch HBM refetch in v5).
template <bool FINAL>
__global__ __launch_bounds__(256) void k_iter(const uint2* __restrict__ src,
                                              void* __restrict__ dst,
                                              const uint2* __restrict__ S,
                                              const int4* __restrict__ desc,
                                              const int* __restrict__ cnt_p,
                                              const int* __restrict__ col_s) {
    int wgid = (blockIdx.x * 256 + threadIdx.x) >> 6;
    int lane = threadIdx.x & 63;
    int nw = gridDim.x << 2;
    int cn = *cnt_p;

    int s = lane >> 3;     // edge slot 0..7
    int q = lane & 7;      // uint2 slot within 64B chunk row

    int jstart = blockIdx.x & 3;   // XCD-staggered chunk start
    for (int t = 0; t < 4; t++) {
        int j = (jstart + t) & 3;
        const uint2* sj = src + (size_t)j * cn * 8 + q;
        const uint2* Sj = S + (size_t)j * cn * 8 + q;
        uint2* dj = (uint2*)dst + (size_t)j * cn * 8 + q;
        for (int i = wgid; i < cn; i += nw) {
            int4 dsc = desc[i];
            int beg = __builtin_amdgcn_readfirstlane(dsc.y);
            int end = __builtin_amdgcn_readfirstlane(dsc.z);

            float a0 = 0, a1 = 0, a2 = 0, a3 = 0;
            float b0 = 0, b1 = 0, b2 = 0, b3 = 0;
            if (s == 0) {
                uint2 sv = Sj[(size_t)i * 8];
                __half2 h; float2 v;
                __builtin_memcpy(&h, &sv.x, 4); v = __half22float2(h); a0 = v.x; a1 = v.y;
                __builtin_memcpy(&h, &sv.y, 4); v = __half22float2(h); a2 = v.x; a3 = v.y;
            }
            int e = beg;
            for (; e + 16 <= end; e += 16) {
                int c0 = col_s[e + s];
                int c1 = col_s[e + 8 + s];
                uint2 g0 = sj[(size_t)c0 * 8];
                uint2 g1 = sj[(size_t)c1 * 8];
                __half2 h; float2 v;
                __builtin_memcpy(&h, &g0.x, 4); v = __half22float2(h); a0 += v.x; a1 += v.y;
                __builtin_memcpy(&h, &g0.y, 4); v = __half22float2(h); a2 += v.x; a3 += v.y;
                __builtin_memcpy(&h, &g1.x, 4); v = __half22float2(h); b0 += v.x; b1 += v.y;
                __builtin_memcpy(&h, &g1.y, 4); v = __half22float2(h); b2 += v.x; b3 += v.y;
            }
            if (e + 8 <= end) {
                int c = col_s[e + s];
                uint2 g = sj[(size_t)c * 8];
                __half2 h; float2 v;
                __builtin_memcpy(&h, &g.x, 4); v = __half22float2(h); a0 += v.x; a1 += v.y;
                __builtin_memcpy(&h, &g.y, 4); v = __half22float2(h); a2 += v.x; a3 += v.y;
                e += 8;
            }
            int rem = end - e;
            if (s < rem) {
                int c = col_s[e + s];
                uint2 g = sj[(size_t)c * 8];
                __half2 h; float2 v;
                __builtin_memcpy(&h, &g.x, 4); v = __half22float2(h); b0 += v.x; b1 += v.y;
                __builtin_memcpy(&h, &g.y, 4); v = __half22float2(h); b2 += v.x; b3 += v.y;
            }
            a0 += b0; a1 += b1; a2 += b2; a3 += b3;
            a0 += __shfl_xor(a0, 8, 64); a0 += __shfl_xor(a0, 16, 64); a0 += __shfl_xor(a0, 32, 64);
            a1 += __shfl_xor(a1, 8, 64); a1 += __shfl_xor(a1, 16, 64); a1 += __shfl_xor(a1, 32, 64);
            a2 += __shfl_xor(a2, 8, 64); a2 += __shfl_xor(a2, 16, 64); a2 += __shfl_xor(a2, 32, 64);
            a3 += __shfl_xor(a3, 8, 64); a3 += __shfl_xor(a3, 16, 64); a3 += __shfl_xor(a3, 32, 64);

            if (s == 0) {
                float d = __int_as_float(dsc.w);
                if (FINAL) {
                    int r = __builtin_amdgcn_readfirstlane(dsc.x);
                    ((float4*)dst)[(size_t)r * 32 + j * 8 + q] =
                        make_float4(d * a0, d * a1, d * a2, d * a3);
                } else {
                    float ss = d * d;
                    __half2 h0 = __floats2half2_rn(ss * a0, ss * a1);
                    __half2 h1 = __floats2half2_rn(ss * a2, ss * a3);
                    uint2 o;
                    __builtin_memcpy(&o.x, &h0, 4);
                    __builtin_memcpy(&o.y, &h1, 4);
                    dj[(size_t)i * 8] = o;
                }
            }
        }
    }
}

extern "C" void kernel_launch(void* const* d_in, const int* in_sizes, int n_in,
                              void* d_out, int out_size, void* d_ws, size_t ws_size,
                              hipStream_t stream) {
    const float* x = (const float*)d_in[0];
    const int* ei = (const int*)d_in[1];
    const void* mraw = d_in[2];

    const int N = in_sizes[0] / D;     // 100000
    const int E = in_sizes[1] / 2;     // 3200000
    const int* row = ei;
    const int* col = ei + E;

    char* ws = (char*)d_ws;
    size_t off = 0;
    uint2* uA = (uint2*)(ws + off);         off += (size_t)N * D * 2;   // fp16 u buffers (chunked)
    uint2* uB = (uint2*)(ws + off);         off += (size_t)N * D * 2;
    uint2* S  = (uint2*)(ws + off);         off += (size_t)N * D * 2;   // fp16 S_fix (chunked)
    int* col_s = (int*)(ws + off);          off += (size_t)E * 4;       // CSR cols (filtered, split)
    int* row_off = (int*)(ws + off);        off += (size_t)(N + 1) * 4;
    int* zblock = (int*)(ws + off);         off += (size_t)(2 * N) * 4; // cur_m|cur_u (memset)
    int* cur_m = zblock;
    int* cur_u = zblock + N;
    int* rdeg = (int*)(ws + off);           off += (size_t)N * 4;
    float* dis = (float*)(ws + off);        off += (size_t)N * 4;
    int* rows_c = (int*)(ws + off);         off += (size_t)N * 4;
    int* nm = (int*)(ws + off);             off += (size_t)N * 4;
    int* cpos = (int*)(ws + off);           off += (size_t)(N + 1) * 4;
    unsigned char* m8 = (unsigned char*)(ws + off); off += (size_t)N;
    off = (off + 255) & ~(size_t)255;
    int* csum = (int*)(ws + off);           off += 256 * 4;
    int* csum2 = (int*)(ws + off);          off += 256 * 4;
    int* flag = (int*)(ws + off);           off += 4;
    off = (off + 255) & ~(size_t)255;
    int4* desc_i = (int4*)(ws + off);       off += (size_t)N * 16;
    int4* desc_s = (int4*)(ws + off);       off += (size_t)N * 16;

    const int* cnt_p = cpos + N;   // total unmasked count, written by scan

    // histogram scratch: aliases uA+uB (written only later by k_sfix / k_iter)
    unsigned int* sc = (unsigned int*)ws;

    (void)hipMemsetAsync(zblock, 0, (size_t)(2 * N) * 4, stream);

    int nb = N < 16384 ? N : 16384;
    k_detect<<<1, 256, 0, stream>>>((const unsigned char*)mraw, nb, flag);
    k_mask<<<(N + 255) / 256, 256, 0, stream>>>(mraw, flag, m8, nm, N);

    // degree histograms: col -> dis, row -> rdeg (mask applied at reduce)
    const int R = (N + (1 << HBITS) - 1) >> HBITS;   // 4 ranges of 32768
    const int Bp = 128;                              // slice <= 25008 < 65536
    int per = ((E + Bp - 1) / Bp + 15) & ~15;
    int rwords = (R << (HBITS - 1));
    k_hist<<<R * Bp, 256, 0, stream>>>(col, E, Bp, per, sc);
    k_red<0><<<(rwords + 255) / 256, 256, 0, stream>>>(sc, Bp, m8, dis, rdeg, N, R);
    k_hist<<<R * Bp, 256, 0, stream>>>(row, E, Bp, per, sc);
    k_red<1><<<(rwords + 255) / 256, 256, 0, stream>>>(sc, Bp, m8, dis, rdeg, N, R);

    int nch = (N + 2047) / 2048;
    // scan rdeg -> row_off
    k_scan1<<<nch, 256, 0, stream>>>(rdeg, csum, N);
    k_scan2<<<1, 64, 0, stream>>>(csum, nch, row_off, N);
    k_scan3<<<nch, 256, 0, stream>>>(rdeg, csum, row_off, N);
    // scan !mask -> cpos (ordered compaction positions), cpos[N] = cnt
    k_scan1<<<nch, 256, 0, stream>>>(nm, csum2, N);
    k_scan2<<<1, 64, 0, stream>>>(csum2, nch, cpos, N);
    k_scan3<<<nch, 256, 0, stream>>>(nm, csum2, cpos, N);
    k_fill<<<(N + 255) / 256, 256, 0, stream>>>(m8, cpos, rows_c, N);

    k_scatter<<<(E + 255) / 256, 256, 0, stream>>>(row, col, E, m8, row_off, cpos,
                                                   cur_m, cur_u, col_s);
    k_desc<<<(N + 255) / 256, 256, 0, stream>>>(rows_c, cnt_p, row_off, cur_m, dis,
                                                desc_i, desc_s);

    int nvec = N * (D / 4);
    k_init<<<(nvec + 255) / 256, 256, 0, stream>>>(x, m8, (float*)d_out, nvec);

    const int PBLK = 2048;   // persistent grid: 8192 waves, all co-resident (8 blk/CU)
    k_sfix<<<PBLK, 256, 0, stream>>>(x, dis, desc_s, cnt_p, col_s, S, uA);

    // u1 in uA; 18 fp16 chunk-phased iterations, then final fp32 iteration -> d_out
    uint2* src = uA;
    uint2* dst = uB;
    for (int it = 0; it < N_ITER - 2; it++) {
        k_iter<false><<<PBLK, 256, 0, stream>>>(src, dst, S, desc_i, cnt_p, col_s);
        uint2* t = src; src = dst; dst = t;
    }
    k_iter<true><<<PBLK, 256, 0, stream>>>(src, d_out, S, desc_i, cnt_p, col_s);
}

// Round 8
// 1003.502 us; speedup vs baseline: 2.2329x; 1.5428x over previous
//
#include <hip/hip_runtime.h>
#include <hip/hip_fp16.h>

#define D 128
#define N_ITER 20
#define HBITS 15                  // 32768 nodes per range
#define HWORDS (1 << (HBITS - 1)) // 16384 packed uint16-pair words = 64 KB LDS

// ---------------- mask dtype detection (sampled prefix is sufficient) ----------------
__global__ void k_detect(const unsigned char* __restrict__ m, int nbytes, int* flag) {
    __shared__ int s;
    if (threadIdx.x == 0) s = 0;
    __syncthreads();
    int c = 0;
    for (int i = threadIdx.x; i < nbytes; i += 256)
        if ((i & 3) && m[i]) c++;
    atomicAdd(&s, c);
    __syncthreads();
    if (threadIdx.x == 0) *flag = (s > 0) ? 1 : 0;
}

__global__ void k_mask(const void* __restrict__ mraw, const int* __restrict__ flag,
                       unsigned char* __restrict__ m8, int* __restrict__ nm, int n) {
    int i = blockIdx.x * 256 + threadIdx.x;
    if (i >= n) return;
    unsigned char v;
    if (*flag) {
        v = ((const unsigned char*)mraw)[i] != 0;
    } else {
        v = ((const int*)mraw)[i] != 0;
    }
    m8[i] = v;
    nm[i] = v ? 0 : 1;
}

// ---------------- histogram: range-partitioned, LDS-privatized, packed u16 ----------
__global__ __launch_bounds__(256) void k_hist(const int* __restrict__ keys, int E,
                                              int Bp, int per,
                                              unsigned int* __restrict__ sc) {
    __shared__ unsigned int h[HWORDS];
    int r = blockIdx.x / Bp;
    int b = blockIdx.x - r * Bp;
    for (int i = threadIdx.x; i < HWORDS; i += 256) h[i] = 0;
    __syncthreads();
    int lo = r << HBITS;
    int beg = b * per;
    int end = min(beg + per, E);
    int e = beg + (threadIdx.x << 2);
    for (; e + 3 < end; e += 1024) {
        int4 k4 = *(const int4*)(keys + e);
        int k;
        k = k4.x - lo; if ((unsigned)k < (unsigned)(1 << HBITS)) atomicAdd(&h[k >> 1], 1u << ((k & 1) << 4));
        k = k4.y - lo; if ((unsigned)k < (unsigned)(1 << HBITS)) atomicAdd(&h[k >> 1], 1u << ((k & 1) << 4));
        k = k4.z - lo; if ((unsigned)k < (unsigned)(1 << HBITS)) atomicAdd(&h[k >> 1], 1u << ((k & 1) << 4));
        k = k4.w - lo; if ((unsigned)k < (unsigned)(1 << HBITS)) atomicAdd(&h[k >> 1], 1u << ((k & 1) << 4));
    }
    for (int ee = e; ee < end && ee < e + 4; ee++) {
        int k = keys[ee] - lo;
        if ((unsigned)k < (unsigned)(1 << HBITS)) atomicAdd(&h[k >> 1], 1u << ((k & 1) << 4));
    }
    __syncthreads();
    unsigned int* out = sc + ((size_t)blockIdx.x << (HBITS - 1));
    for (int i = threadIdx.x; i < HWORDS; i += 256) out[i] = h[i];
}

// ---------------- reduce per-block histograms -> dis (MODE 0) or rdeg (MODE 1) ------
template <int MODE>
__global__ void k_red(const unsigned int* __restrict__ sc, int Bp,
                      const unsigned char* __restrict__ m8,
                      float* __restrict__ dis, int* __restrict__ rdeg, int N, int R) {
    int w = blockIdx.x * 256 + threadIdx.x;
    if (w >= (R << (HBITS - 1))) return;
    int r = w >> (HBITS - 1);
    int word = w & (HWORDS - 1);
    int n0 = (r << HBITS) + (word << 1);
    if (n0 >= N) return;
    const unsigned int* p = sc + (((size_t)r * Bp) << (HBITS - 1)) + word;
    unsigned int slo = 0, shi = 0;
    for (int b = 0; b < Bp; b++) {
        unsigned int v = p[(size_t)b << (HBITS - 1)];
        slo += v & 0xffffu;
        shi += v >> 16;
    }
    if (MODE == 0) {
        dis[n0] = slo ? rsqrtf((float)slo) : 0.f;
        if (n0 + 1 < N) dis[n0 + 1] = shi ? rsqrtf((float)shi) : 0.f;
    } else {
        rdeg[n0] = m8[n0] ? 0 : (int)slo;
        if (n0 + 1 < N) rdeg[n0 + 1] = m8[n0 + 1] ? 0 : (int)shi;
    }
}

// ---------------- exclusive scan (generic over input array) ----------------
__global__ void k_scan1(const int* __restrict__ a, int* __restrict__ csum, int n) {
    __shared__ int sh[256];
    int base = blockIdx.x * 2048;
    int t = threadIdx.x;
    int s = 0;
    for (int j = 0; j < 8; j++) {
        int i = base + t * 8 + j;
        if (i < n) s += a[i];
    }
    sh[t] = s;
    __syncthreads();
    for (int o = 128; o > 0; o >>= 1) {
        if (t < o) sh[t] += sh[t + o];
        __syncthreads();
    }
    if (t == 0) csum[blockIdx.x] = sh[0];
}

__global__ void k_scan2(int* __restrict__ csum, int nch, int* __restrict__ out_off, int n) {
    if (threadIdx.x == 0) {
        int acc = 0;
        for (int i = 0; i < nch; i++) { int v = csum[i]; csum[i] = acc; acc += v; }
        out_off[n] = acc;
    }
}

__global__ void k_scan3(const int* __restrict__ a, const int* __restrict__ csum,
                        int* __restrict__ out_off, int n) {
    __shared__ int sh[256];
    int base = blockIdx.x * 2048;
    int t = threadIdx.x;
    int loc[8];
    int s = 0;
    for (int j = 0; j < 8; j++) {
        int i = base + t * 8 + j;
        int v = (i < n) ? a[i] : 0;
        loc[j] = s;
        s += v;
    }
    sh[t] = s;
    __syncthreads();
    for (int o = 1; o < 256; o <<= 1) {
        int v = (t >= o) ? sh[t - o] : 0;
        __syncthreads();
        sh[t] += v;
        __syncthreads();
    }
    int toff = csum[blockIdx.x] + ((t > 0) ? sh[t - 1] : 0);
    for (int j = 0; j < 8; j++) {
        int i = base + t * 8 + j;
        if (i < n) out_off[i] = toff + loc[j];
    }
}

// ---------------- ordered compact: rows_c[cpos[i]] = i for unmasked i ----------------
__global__ void k_fill(const unsigned char* __restrict__ m8, const int* __restrict__ cpos,
                       int* __restrict__ rows_c, int n) {
    int i = blockIdx.x * 256 + threadIdx.x;
    if (i >= n) return;
    if (!m8[i]) rows_c[cpos[i]] = i;
}

// ---------------- scatter: masked cols (orig id) front / unmasked cols (compact) back
__global__ void k_scatter(const int* __restrict__ row, const int* __restrict__ col, int E,
                          const unsigned char* __restrict__ m8,
                          const int* __restrict__ row_off,
                          const int* __restrict__ cpos,
                          int* __restrict__ cur_m, int* __restrict__ cur_u,
                          int* __restrict__ col_s) {
    int e = blockIdx.x * 256 + threadIdx.x;
    if (e >= E) return;
    int r = row[e];
    if (m8[r]) return;
    int c = col[e];
    int p;
    if (m8[c]) {
        p = row_off[r] + atomicAdd(&cur_m[r], 1);
        col_s[p] = c;                 // original id: k_sfix gathers x[c]
    } else {
        p = row_off[r + 1] - 1 - atomicAdd(&cur_u[r], 1);
        col_s[p] = cpos[c];           // compact id: k_iter gathers dense u
    }
}

// ---------------- per-row descriptors; .w carries dis[r] bits ----------------
__global__ void k_desc(const int* __restrict__ rows_c, const int* __restrict__ cnt_p,
                       const int* __restrict__ row_off, const int* __restrict__ cur_m,
                       const float* __restrict__ dis,
                       int4* __restrict__ di, int4* __restrict__ dsx) {
    int i = blockIdx.x * 256 + threadIdx.x;
    if (i >= *cnt_p) return;
    int r = rows_c[i];
    int ro = row_off[r];
    int cm = cur_m[r];
    int ro1 = row_off[r + 1];
    int db = __float_as_int(dis[r]);
    di[i]  = make_int4(r, ro + cm, ro1, db);  // unmasked-col edge range (per-iteration gather)
    dsx[i] = make_int4(r, ro, ro + cm, db);   // masked-col edge range (S_fix)
}

// ---------------- init: masked rows of d_out = x ----------------
__global__ void k_init(const float* __restrict__ x, const unsigned char* __restrict__ m8,
                       float* __restrict__ out, int nvec) {
    int i = blockIdx.x * 256 + threadIdx.x;  // float4 index, 32 per node
    if (i >= nvec) return;
    int node = i >> 5;
    if (m8[node]) ((float4*)out)[i] = ((const float4*)x)[i];
}

// ---------------- S_fix[i] = sum over masked cols of dis[c]*x[c] ---------------------
// Dense compact fp16 layout: row i occupies uint2 slots i*32 + 0..31 (256B).
// Also writes u1[i] = dis[r]^2 * S_fix[i].
__global__ __launch_bounds__(256) void k_sfix(const float* __restrict__ x,
                                              const float* __restrict__ dis,
                                              const int4* __restrict__ desc,
                                              const int* __restrict__ cnt_p,
                                              const int* __restrict__ col_s,
                                              uint2* __restrict__ S,
                                              uint2* __restrict__ u1) {
    int wgid = (blockIdx.x * 256 + threadIdx.x) >> 6;
    int lane = threadIdx.x & 63;
    int nw = gridDim.x << 2;
    int cn = *cnt_p;

    int s = lane >> 5;     // edge slot 0..1
    int f = lane & 31;     // float4 slot within 512B row
    const float4* xb = (const float4*)x + f;

    for (int wid = wgid; wid < cn; wid += nw) {
        int4 dsc = desc[wid];
        int beg = __builtin_amdgcn_readfirstlane(dsc.y);
        int end = __builtin_amdgcn_readfirstlane(dsc.z);

        float a0 = 0, a1 = 0, a2 = 0, a3 = 0;
        float b0 = 0, b1 = 0, b2 = 0, b3 = 0;
        int e = beg;
        for (; e + 8 <= end; e += 8) {
            int c0 = col_s[e + s],     c1 = col_s[e + 2 + s];
            int c2 = col_s[e + 4 + s], c3 = col_s[e + 6 + s];
            float w0 = dis[c0], w1 = dis[c1], w2 = dis[c2], w3 = dis[c3];
            float4 v0 = xb[(size_t)c0 * 32];
            float4 v1 = xb[(size_t)c1 * 32];
            float4 v2 = xb[(size_t)c2 * 32];
            float4 v3 = xb[(size_t)c3 * 32];
            a0 += w0 * v0.x; a1 += w0 * v0.y; a2 += w0 * v0.z; a3 += w0 * v0.w;
            b0 += w1 * v1.x; b1 += w1 * v1.y; b2 += w1 * v1.z; b3 += w1 * v1.w;
            a0 += w2 * v2.x; a1 += w2 * v2.y; a2 += w2 * v2.z; a3 += w2 * v2.w;
            b0 += w3 * v3.x; b1 += w3 * v3.y; b2 += w3 * v3.z; b3 += w3 * v3.w;
        }
        for (; e + 2 <= end; e += 2) {
            int c = col_s[e + s];
            float w = dis[c];
            float4 v = xb[(size_t)c * 32];
            a0 += w * v.x; a1 += w * v.y; a2 += w * v.z; a3 += w * v.w;
        }
        if (e < end && s == 0) {
            int c = col_s[e];
            float w = dis[c];
            float4 v = xb[(size_t)c * 32];
            a0 += w * v.x; a1 += w * v.y; a2 += w * v.z; a3 += w * v.w;
        }
        a0 += b0; a1 += b1; a2 += b2; a3 += b3;
        a0 += __shfl_xor(a0, 32, 64);
        a1 += __shfl_xor(a1, 32, 64);
        a2 += __shfl_xor(a2, 32, 64);
        a3 += __shfl_xor(a3, 32, 64);
        if (lane < 32) {
            size_t so = (size_t)wid * 32 + f;
            __half2 h0 = __floats2half2_rn(a0, a1);
            __half2 h1 = __floats2half2_rn(a2, a3);
            uint2 o;
            __builtin_memcpy(&o.x, &h0, 4);
            __builtin_memcpy(&o.y, &h1, 4);
            S[so] = o;
            float dd = __int_as_float(dsc.w);
            float ss = dd * dd;
            __half2 g0 = __floats2half2_rn(ss * a0, ss * a1);
            __half2 g1 = __floats2half2_rn(ss * a2, ss * a3);
            uint2 o2;
            __builtin_memcpy(&o2.x, &g0, 4);
            __builtin_memcpy(&o2.y, &g1, 4);
            u1[so] = o2;
        }
    }
}

// ---------------- iteration: 16-lane x 16B row-major, dense compact indexing ---------
// u_new[i] = dis^2 * (S_fix[i] + sum u[c]); final: out[r] = dis * (...) fp32.
// R4-proven structure (42us/iter): 4 gathers in flight, low VGPR, ~8 waves/SIMD.
__device__ __forceinline__ void acc8(const uint4& g,
                                     float& x0, float& x1, float& x2, float& x3,
                                     float& x4, float& x5, float& x6, float& x7) {
    __half2 h; float2 v;
    __builtin_memcpy(&h, &g.x, 4); v = __half22float2(h); x0 += v.x; x1 += v.y;
    __builtin_memcpy(&h, &g.y, 4); v = __half22float2(h); x2 += v.x; x3 += v.y;
    __builtin_memcpy(&h, &g.z, 4); v = __half22float2(h); x4 += v.x; x5 += v.y;
    __builtin_memcpy(&h, &g.w, 4); v = __half22float2(h); x6 += v.x; x7 += v.y;
}

template <bool FINAL>
__global__ __launch_bounds__(256) void k_iter(const uint4* __restrict__ src,
                                              void* __restrict__ dst,
                                              const uint4* __restrict__ S,
                                              const int4* __restrict__ desc,
                                              const int* __restrict__ cnt_p,
                                              const int* __restrict__ col_s) {
    int wgid = (blockIdx.x * 256 + threadIdx.x) >> 6;
    int lane = threadIdx.x & 63;
    int nw = gridDim.x << 2;
    int cn = *cnt_p;

    int s = lane >> 4;     // edge slot 0..3
    int f = lane & 15;     // uint4 (half8) slot, row stride 16
    const uint4* cb = src + f;
    const uint4* Sb = S + f;

    for (int i = wgid; i < cn; i += nw) {
        int4 dsc = desc[i];
        int beg = __builtin_amdgcn_readfirstlane(dsc.y);
        int end = __builtin_amdgcn_readfirstlane(dsc.z);

        float a0 = 0, a1 = 0, a2 = 0, a3 = 0, a4 = 0, a5 = 0, a6 = 0, a7 = 0;
        float b0 = 0, b1 = 0, b2 = 0, b3 = 0, b4 = 0, b5 = 0, b6 = 0, b7 = 0;
        if (s == 0) {
            uint4 sv = Sb[(size_t)i * 16];
            acc8(sv, a0, a1, a2, a3, a4, a5, a6, a7);
        }

        int e = beg;
        for (; e + 16 <= end; e += 16) {
            int c0 = col_s[e + s];
            int c1 = col_s[e + 4 + s];
            int c2 = col_s[e + 8 + s];
            int c3 = col_s[e + 12 + s];
            uint4 g0 = cb[(size_t)c0 * 16];
            uint4 g1 = cb[(size_t)c1 * 16];
            uint4 g2 = cb[(size_t)c2 * 16];
            uint4 g3 = cb[(size_t)c3 * 16];
            acc8(g0, a0, a1, a2, a3, a4, a5, a6, a7);
            acc8(g1, b0, b1, b2, b3, b4, b5, b6, b7);
            acc8(g2, a0, a1, a2, a3, a4, a5, a6, a7);
            acc8(g3, b0, b1, b2, b3, b4, b5, b6, b7);
        }
        for (; e + 4 <= end; e += 4) {
            int c = col_s[e + s];
            uint4 g = cb[(size_t)c * 16];
            acc8(g, a0, a1, a2, a3, a4, a5, a6, a7);
        }
        int rem = end - e;
        if (s < rem) {
            int c = col_s[e + s];
            uint4 g = cb[(size_t)c * 16];
            acc8(g, a0, a1, a2, a3, a4, a5, a6, a7);
        }
        a0 += b0; a1 += b1; a2 += b2; a3 += b3;
        a4 += b4; a5 += b5; a6 += b6; a7 += b7;
        a0 += __shfl_xor(a0, 16, 64); a0 += __shfl_xor(a0, 32, 64);
        a1 += __shfl_xor(a1, 16, 64); a1 += __shfl_xor(a1, 32, 64);
        a2 += __shfl_xor(a2, 16, 64); a2 += __shfl_xor(a2, 32, 64);
        a3 += __shfl_xor(a3, 16, 64); a3 += __shfl_xor(a3, 32, 64);
        a4 += __shfl_xor(a4, 16, 64); a4 += __shfl_xor(a4, 32, 64);
        a5 += __shfl_xor(a5, 16, 64); a5 += __shfl_xor(a5, 32, 64);
        a6 += __shfl_xor(a6, 16, 64); a6 += __shfl_xor(a6, 32, 64);
        a7 += __shfl_xor(a7, 16, 64); a7 += __shfl_xor(a7, 32, 64);

        if (lane < 16) {
            float d = __int_as_float(dsc.w);
            if (FINAL) {
                int r = __builtin_amdgcn_readfirstlane(dsc.x);
                float4* o = (float4*)dst + (size_t)r * 32 + f * 2;
                o[0] = make_float4(d * a0, d * a1, d * a2, d * a3);
                o[1] = make_float4(d * a4, d * a5, d * a6, d * a7);
            } else {
                float ss = d * d;
                __half2 h0 = __floats2half2_rn(ss * a0, ss * a1);
                __half2 h1 = __floats2half2_rn(ss * a2, ss * a3);
                __half2 h2 = __floats2half2_rn(ss * a4, ss * a5);
                __half2 h3 = __floats2half2_rn(ss * a6, ss * a7);
                uint4 o;
                __builtin_memcpy(&o.x, &h0, 4);
                __builtin_memcpy(&o.y, &h1, 4);
                __builtin_memcpy(&o.z, &h2, 4);
                __builtin_memcpy(&o.w, &h3, 4);
                ((uint4*)dst)[(size_t)i * 16 + f] = o;
            }
        }
    }
}

extern "C" void kernel_launch(void* const* d_in, const int* in_sizes, int n_in,
                              void* d_out, int out_size, void* d_ws, size_t ws_size,
                              hipStream_t stream) {
    const float* x = (const float*)d_in[0];
    const int* ei = (const int*)d_in[1];
    const void* mraw = d_in[2];

    const int N = in_sizes[0] / D;     // 100000
    const int E = in_sizes[1] / 2;     // 3200000
    const int* row = ei;
    const int* col = ei + E;

    char* ws = (char*)d_ws;
    size_t off = 0;
    uint2* uA = (uint2*)(ws + off);         off += (size_t)N * D * 2;   // fp16 u buffers (dense compact)
    uint2* uB = (uint2*)(ws + off);         off += (size_t)N * D * 2;
    uint2* S  = (uint2*)(ws + off);         off += (size_t)N * D * 2;   // fp16 S_fix (dense compact)
    int* col_s = (int*)(ws + off);          off += (size_t)E * 4;       // CSR cols (filtered, split)
    int* row_off = (int*)(ws + off);        off += (size_t)(N + 1) * 4;
    int* zblock = (int*)(ws + off);         off += (size_t)(2 * N) * 4; // cur_m|cur_u (memset)
    int* cur_m = zblock;
    int* cur_u = zblock + N;
    int* rdeg = (int*)(ws + off);           off += (size_t)N * 4;
    float* dis = (float*)(ws + off);        off += (size_t)N * 4;
    int* rows_c = (int*)(ws + off);         off += (size_t)N * 4;
    int* nm = (int*)(ws + off);             off += (size_t)N * 4;
    int* cpos = (int*)(ws + off);           off += (size_t)(N + 1) * 4;
    unsigned char* m8 = (unsigned char*)(ws + off); off += (size_t)N;
    off = (off + 255) & ~(size_t)255;
    int* csum = (int*)(ws + off);           off += 256 * 4;
    int* csum2 = (int*)(ws + off);          off += 256 * 4;
    int* flag = (int*)(ws + off);           off += 4;
    off = (off + 255) & ~(size_t)255;
    int4* desc_i = (int4*)(ws + off);       off += (size_t)N * 16;
    int4* desc_s = (int4*)(ws + off);       off += (size_t)N * 16;

    const int* cnt_p = cpos + N;   // total unmasked count, written by scan

    // histogram scratch: aliases uA+uB (written only later by k_sfix / k_iter)
    unsigned int* sc = (unsigned int*)ws;

    (void)hipMemsetAsync(zblock, 0, (size_t)(2 * N) * 4, stream);

    int nb = N < 16384 ? N : 16384;
    k_detect<<<1, 256, 0, stream>>>((const unsigned char*)mraw, nb, flag);
    k_mask<<<(N + 255) / 256, 256, 0, stream>>>(mraw, flag, m8, nm, N);

    // degree histograms: col -> dis, row -> rdeg (mask applied at reduce)
    const int R = (N + (1 << HBITS) - 1) >> HBITS;   // 4 ranges of 32768
    const int Bp = 128;                              // slice <= 25008 < 65536
    int per = ((E + Bp - 1) / Bp + 15) & ~15;
    int rwords = (R << (HBITS - 1));
    k_hist<<<R * Bp, 256, 0, stream>>>(col, E, Bp, per, sc);
    k_red<0><<<(rwords + 255) / 256, 256, 0, stream>>>(sc, Bp, m8, dis, rdeg, N, R);
    k_hist<<<R * Bp, 256, 0, stream>>>(row, E, Bp, per, sc);
    k_red<1><<<(rwords + 255) / 256, 256, 0, stream>>>(sc, Bp, m8, dis, rdeg, N, R);

    int nch = (N + 2047) / 2048;
    // scan rdeg -> row_off
    k_scan1<<<nch, 256, 0, stream>>>(rdeg, csum, N);
    k_scan2<<<1, 64, 0, stream>>>(csum, nch, row_off, N);
    k_scan3<<<nch, 256, 0, stream>>>(rdeg, csum, row_off, N);
    // scan !mask -> cpos (ordered compaction positions), cpos[N] = cnt
    k_scan1<<<nch, 256, 0, stream>>>(nm, csum2, N);
    k_scan2<<<1, 64, 0, stream>>>(csum2, nch, cpos, N);
    k_scan3<<<nch, 256, 0, stream>>>(nm, csum2, cpos, N);
    k_fill<<<(N + 255) / 256, 256, 0, stream>>>(m8, cpos, rows_c, N);

    k_scatter<<<(E + 255) / 256, 256, 0, stream>>>(row, col, E, m8, row_off, cpos,
                                                   cur_m, cur_u, col_s);
    k_desc<<<(N + 255) / 256, 256, 0, stream>>>(rows_c, cnt_p, row_off, cur_m, dis,
                                                desc_i, desc_s);

    int nvec = N * (D / 4);
    k_init<<<(nvec + 255) / 256, 256, 0, stream>>>(x, m8, (float*)d_out, nvec);

    const int PBLK = 2048;   // persistent grid: 8192 waves, grid-stride over compact rows
    k_sfix<<<PBLK, 256, 0, stream>>>(x, dis, desc_s, cnt_p, col_s, S, uA);

    // u1 in uA; 18 fp16 gather iterations, then final fp32 iteration -> d_out
    uint4* src = (uint4*)uA;
    uint4* dst = (uint4*)uB;
    const uint4* S4 = (const uint4*)S;
    for (int it = 0; it < N_ITER - 2; it++) {
        k_iter<false><<<PBLK, 256, 0, stream>>>(src, dst, S4, desc_i, cnt_p, col_s);
        uint4* t = src; src = dst; dst = t;
    }
    k_iter<true><<<PBLK, 256, 0, stream>>>(src, d_out, S4, desc_i, cnt_p, col_s);
}